// Round 16
// baseline (46.265 us; speedup 1.0000x reference)
//
#include <hip/hip_runtime.h>

#define HW 224
#define CHW (HW*HW)
#define NBLK (28 * 128)
#define RS 256                      // staged row stride in floats (1024 B)

typedef __attribute__((address_space(1))) const unsigned int guint;
typedef __attribute__((address_space(3))) unsigned int luint;

__global__ __launch_bounds__(256) void patch_conv_kernel(
    const float* __restrict__ X,    // [B][3][224][224]
    const float* __restrict__ Wt,   // [3][3][3][3] OIHW
    const float* __restrict__ Bv,   // [3]
    const float* __restrict__ P,    // [3136][48]
    float* __restrict__ out)        // [B][196][768]
{
    const int tid  = threadIdx.x;
    const int lane = tid & 63;
    const int wv   = tid >> 6;

    // XCD-chunked bijective swizzle (won in r15)
    const int n     = blockIdx.x;               // 0..3583
    const int swz   = (n & 7) * (NBLK / 8) + (n >> 3);
    const int strip = swz % 28;                 // 8-row strip within image
    const int b     = swz / 28;                 // image 0..127
    const int y0    = strip * 8;                // block owns rows y0..y0+7
    const int x0    = lane * 4;                 // 0..252
    const bool act  = (x0 < HW);                // lanes 56..63 assist shfl only

    // staged slab: rows y0-1 .. y0+8 (10 rows) x 3 channels, 1024B row stride
    __shared__ float xs[3][10][RS];             // 30720 B

    // ---- zero boundary slab rows (only first/last strip of the image)
    if (strip == 0) {
        for (int i = tid; i < 3 * (RS / 4); i += 256) {
            const int ci = i >> 6, c = (i & 63) * 4;
            *(float4*)&xs[ci][0][c] = make_float4(0.f, 0.f, 0.f, 0.f);
        }
    }
    if (strip == 27) {
        for (int i = tid; i < 3 * (RS / 4); i += 256) {
            const int ci = i >> 6, c = (i & 63) * 4;
            *(float4*)&xs[ci][9][c] = make_float4(0.f, 0.f, 0.f, 0.f);
        }
    }

    // ---- stage 30 rows via global_load_lds DMA, 7-8 per wave, fire-and-forget
    const float* Xb = X + (size_t)b * (3 * CHW);
    const int gl = (lane < 56) ? lane : 55;     // clamp tail lanes (dup read)
    #pragma unroll
    for (int k = 0; k < 8; ++k) {
        const int idx = k * 4 + wv;             // wave-uniform
        if (idx < 30) {
            const int ci = idx / 10, r = idx - ci * 10;
            const int ry = y0 - 1 + r;
            if ((unsigned)ry < HW) {
                const float* gsrc = Xb + ci * CHW + ry * HW + gl * 4;
                __builtin_amdgcn_global_load_lds(
                    (guint*)(const void*)gsrc,
                    (luint*)(void*)&xs[ci][r][0],
                    16, 0, 0);
            }
        }
    }

    // ---- weights (wave-uniform -> SGPRs) + P loads, overlapping the DMA
    float w[81];
    #pragma unroll
    for (int i = 0; i < 81; ++i) w[i] = Wt[i];

    const int y0w  = y0 + wv * 2;               // wave's first output row (even)
    const int nf   = (y0w >> 2) * 56 + lane;    // lane == x0>>2
    const int sub0 = (wv & 1) * 8;              // (y0w&3)*4
    float4 pr[2][3];
    #pragma unroll
    for (int rr = 0; rr < 2; ++rr) {
        #pragma unroll
        for (int co = 0; co < 3; ++co) {
            float4 t = make_float4(0.f, 0.f, 0.f, 0.f);
            if (act)
                t = *(const float4*)(P + nf * 48 + co * 16 + sub0 + rr * 4);
            pr[rr][co] = t;
        }
    }

    __syncthreads();                            // drains DMA (vmcnt) + zeros

    // ---- windows from LDS (conflict-free ds_read_b128) + shfl edges
    float win[3][4][6];
    #pragma unroll
    for (int ci = 0; ci < 3; ++ci) {
        #pragma unroll
        for (int rj = 0; rj < 4; ++rj) {
            const float4 v = *(const float4*)&xs[ci][wv * 2 + rj][x0];
            float lf = __shfl_up(v.w, 1);
            float rt = __shfl_down(v.x, 1);
            if (lane == 0) lf = 0.f;
            if (x0 + 4 >= HW) rt = 0.f;
            win[ci][rj][0] = lf;
            win[ci][rj][1] = v.x; win[ci][rj][2] = v.y;
            win[ci][rj][3] = v.z; win[ci][rj][4] = v.w;
            win[ci][rj][5] = rt;
        }
    }

    if (!act) return;                           // no barriers past this point

    // ---- accumulators: bias + P
    float acc[2][3][4];
    #pragma unroll
    for (int rr = 0; rr < 2; ++rr) {
        #pragma unroll
        for (int co = 0; co < 3; ++co) {
            const float bb = Bv[co];
            acc[rr][co][0] = bb + pr[rr][co].x;
            acc[rr][co][1] = bb + pr[rr][co].y;
            acc[rr][co][2] = bb + pr[rr][co].z;
            acc[rr][co][3] = bb + pr[rr][co].w;
        }
    }

    // ---- 648 FMAs: row0 uses win[.][ky], row1 uses win[.][ky+1]
    #pragma unroll
    for (int ci = 0; ci < 3; ++ci) {
        #pragma unroll
        for (int ky = 0; ky < 3; ++ky) {
            const float* r0 = win[ci][ky];
            const float* r1 = win[ci][ky + 1];
            #pragma unroll
            for (int co = 0; co < 3; ++co) {
                const float w0 = w[((co * 3 + ci) * 3 + ky) * 3 + 0];
                const float w1 = w[((co * 3 + ci) * 3 + ky) * 3 + 1];
                const float w2 = w[((co * 3 + ci) * 3 + ky) * 3 + 2];
                #pragma unroll
                for (int j = 0; j < 4; ++j) {
                    acc[0][co][j] += w0 * r0[j] + w1 * r0[j + 1] + w2 * r0[j + 2];
                    acc[1][co][j] += w0 * r1[j] + w1 * r1[j + 1] + w2 * r1[j + 2];
                }
            }
        }
    }

    // ---- stores: both rows share the same coarse patch (y0w even)
    const int nc = (y0w >> 4) * 14 + (x0 >> 4);
    float* opb = out + (size_t)b * (196 * 768) + nc * 768 + (x0 & 15);
    #pragma unroll
    for (int rr = 0; rr < 2; ++rr) {
        float* op = opb + ((y0w + rr) & 15) * 16;
        #pragma unroll
        for (int co = 0; co < 3; ++co)
            *(float4*)(op + co * 256) =
                make_float4(acc[rr][co][0], acc[rr][co][1],
                            acc[rr][co][2], acc[rr][co][3]);
    }
}

extern "C" void kernel_launch(void* const* d_in, const int* in_sizes, int n_in,
                              void* d_out, int out_size, void* d_ws, size_t ws_size,
                              hipStream_t stream) {
    const float* X  = (const float*)d_in[0];
    const float* Wt = (const float*)d_in[1];
    const float* Bv = (const float*)d_in[2];
    const float* P  = (const float*)d_in[3];
    float* out = (float*)d_out;

    // block = 4 waves = 8 rows, LDS-staged via global_load_lds; XCD swizzle
    patch_conv_kernel<<<NBLK, 256, 0, stream>>>(X, Wt, Bv, P, out);
}

// Round 17
// 39.008 us; speedup vs baseline: 1.1860x; 1.1860x over previous
//
#include <hip/hip_runtime.h>

#define HW 224
#define CHW (HW*HW)
#define NBLK (28 * 128)

__global__ __launch_bounds__(256) void patch_conv_kernel(
    const float* __restrict__ X,    // [B][3][224][224]
    const float* __restrict__ Wt,   // [3][3][3][3] OIHW
    const float* __restrict__ Bv,   // [3]
    const float* __restrict__ P,    // [3136][48]
    float* __restrict__ out)        // [B][196][768]
{
    const int tid  = threadIdx.x;
    const int lane = tid & 63;
    const int wv   = tid >> 6;

    // XCD-aware bijective swizzle: consecutive blockIdx round-robin across the
    // 8 XCDs; remap so each XCD gets 448 contiguous work items = 16 whole
    // images -> strip halos + P slice become per-XCD L2 hits.
    const int n    = blockIdx.x;                // 0..3583
    const int swz  = (n & 7) * (NBLK / 8) + (n >> 3);
    const int strip = swz % 28;                 // 8-row strip within image
    const int b     = swz / 28;                 // image 0..127

    const int y0   = strip * 8 + wv * 2;        // even; wave owns rows y0, y0+1
    const int x0   = lane * 4;                  // 0..252
    const bool act = (x0 < HW);                 // lanes 56..63 assist shfl only

    // ---- weights: wave-uniform -> SGPRs
    float w[81];
    #pragma unroll
    for (int i = 0; i < 81; ++i) w[i] = Wt[i];

    const float* Xb = X + (size_t)b * (3 * CHW);

    // ---- issue ALL 12 X loads up-front (rows y0-1..y0+2 x 3 channels)
    float4 v[3][4];
    #pragma unroll
    for (int ci = 0; ci < 3; ++ci) {
        #pragma unroll
        for (int rj = 0; rj < 4; ++rj) {
            const int ry = y0 - 1 + rj;
            float4 t = make_float4(0.f, 0.f, 0.f, 0.f);
            if ((unsigned)ry < HW && act)
                t = *(const float4*)(Xb + ci * CHW + ry * HW + x0);
            v[ci][rj] = t;
        }
    }

    // ---- 6 P loads, also up-front (rows y0,y0+1 in the SAME fine row: y0 even)
    const int nf   = (y0 >> 2) * 56 + lane;     // lane == x0>>2
    const int sub0 = (y0 & 3) * 4;              // 0 or 8
    float4 pr[2][3];
    #pragma unroll
    for (int rr = 0; rr < 2; ++rr) {
        #pragma unroll
        for (int co = 0; co < 3; ++co) {
            float4 t = make_float4(0.f, 0.f, 0.f, 0.f);
            if (act)
                t = *(const float4*)(P + nf * 48 + co * 16 + sub0 + rr * 4);
            pr[rr][co] = t;
        }
    }

    // ---- edges via shfl (all 64 lanes participate)
    float win[3][4][6];
    #pragma unroll
    for (int ci = 0; ci < 3; ++ci) {
        #pragma unroll
        for (int rj = 0; rj < 4; ++rj) {
            float lf = __shfl_up(v[ci][rj].w, 1);
            float rt = __shfl_down(v[ci][rj].x, 1);
            if (lane == 0) lf = 0.f;
            if (x0 + 4 >= HW) rt = 0.f;
            win[ci][rj][0] = lf;
            win[ci][rj][1] = v[ci][rj].x; win[ci][rj][2] = v[ci][rj].y;
            win[ci][rj][3] = v[ci][rj].z; win[ci][rj][4] = v[ci][rj].w;
            win[ci][rj][5] = rt;
        }
    }

    if (!act) return;

    // ---- accumulators: bias + P
    float acc[2][3][4];
    #pragma unroll
    for (int rr = 0; rr < 2; ++rr) {
        #pragma unroll
        for (int co = 0; co < 3; ++co) {
            const float bb = Bv[co];
            acc[rr][co][0] = bb + pr[rr][co].x;
            acc[rr][co][1] = bb + pr[rr][co].y;
            acc[rr][co][2] = bb + pr[rr][co].z;
            acc[rr][co][3] = bb + pr[rr][co].w;
        }
    }

    // ---- 648 FMAs: row0 uses win[.][ky], row1 uses win[.][ky+1]
    #pragma unroll
    for (int ci = 0; ci < 3; ++ci) {
        #pragma unroll
        for (int ky = 0; ky < 3; ++ky) {
            const float* r0 = win[ci][ky];
            const float* r1 = win[ci][ky + 1];
            #pragma unroll
            for (int co = 0; co < 3; ++co) {
                const float w0 = w[((co * 3 + ci) * 3 + ky) * 3 + 0];
                const float w1 = w[((co * 3 + ci) * 3 + ky) * 3 + 1];
                const float w2 = w[((co * 3 + ci) * 3 + ky) * 3 + 2];
                #pragma unroll
                for (int j = 0; j < 4; ++j) {
                    acc[0][co][j] += w0 * r0[j] + w1 * r0[j + 1] + w2 * r0[j + 2];
                    acc[1][co][j] += w0 * r1[j] + w1 * r1[j + 1] + w2 * r1[j + 2];
                }
            }
        }
    }

    // ---- stores: both rows share the same coarse patch (y0 even)
    const int nc = (y0 >> 4) * 14 + (x0 >> 4);
    float* opb = out + (size_t)b * (196 * 768) + nc * 768 + (x0 & 15);
    #pragma unroll
    for (int rr = 0; rr < 2; ++rr) {
        float* op = opb + ((y0 + rr) & 15) * 16;
        #pragma unroll
        for (int co = 0; co < 3; ++co)
            *(float4*)(op + co * 256) =
                make_float4(acc[rr][co][0], acc[rr][co][1],
                            acc[rr][co][2], acc[rr][co][3]);
    }
}

extern "C" void kernel_launch(void* const* d_in, const int* in_sizes, int n_in,
                              void* d_out, int out_size, void* d_ws, size_t ws_size,
                              hipStream_t stream) {
    const float* X  = (const float*)d_in[0];
    const float* Wt = (const float*)d_in[1];
    const float* Bv = (const float*)d_in[2];
    const float* P  = (const float*)d_in[3];
    float* out = (float*)d_out;

    // wave = 2 rows; block = 4 waves = 8 rows; 1D grid with XCD-chunked swizzle
    patch_conv_kernel<<<NBLK, 256, 0, stream>>>(X, Wt, Bv, P, out);
}